// Round 13
// baseline (1098.964 us; speedup 1.0000x reference)
//
#include <hip/hip_runtime.h>

// RATSQL relation-aware transformer layer, MI355X.
// Round 13: PV d-slice restructure. R12 attn2_k = 218us, L2-bound: 4 waves
// each read full 128KB vT (2.6 GB L2/dispatch, ~77us at 34.5 TB/s). Waves now
// partition d (8 each), lanes carry all 4 i's -> vT 512->128 KB/block, total
// L2 1.18 GB -> ~34us floor. QKV fused into one 384-block dispatch.

typedef unsigned short bf16;

__global__ void cp_k(const float* __restrict__ in, float* __restrict__ out, int n) {
  int i = blockIdx.x * blockDim.x + threadIdx.x;
  int st = gridDim.x * blockDim.x;
  for (; i < n; i += st) out[i] = in[i];
}

// ---------- tiled GEMM: C = act(A(MxK) @ B(KxN) + bias), all fp32 ----------
__global__ __launch_bounds__(256) void gemm_k(
    const float* __restrict__ A, const float* __restrict__ Bw, size_t beoff,
    const float* __restrict__ bias, size_t boff, float* __restrict__ C,
    int M, int N, int K, int kvmode, int do_relu)
{
  __shared__ float As[16][68];
  __shared__ float Bs[16][68];
  int tid = threadIdx.x;
  int m0 = blockIdx.y * 64, n0 = blockIdx.x * 64;
  int tx = tid & 15, ty = tid >> 4;
  int arow = tid >> 2, acol = (tid & 3) << 2;
  int brow = tid >> 4, bcol = (tid & 15) << 2;
  float acc[4][4] = {{0.f}};
  for (int k0 = 0; k0 < K; k0 += 16) {
    float4 a4 = *(const float4*)(A + (size_t)(m0 + arow) * K + k0 + acol);
    As[acol + 0][arow] = a4.x;
    As[acol + 1][arow] = a4.y;
    As[acol + 2][arow] = a4.z;
    As[acol + 3][arow] = a4.w;
    float4 b4 = *(const float4*)(Bw + beoff + (size_t)(k0 + brow) * N + n0 + bcol);
    Bs[brow][bcol + 0] = b4.x;
    Bs[brow][bcol + 1] = b4.y;
    Bs[brow][bcol + 2] = b4.z;
    Bs[brow][bcol + 3] = b4.w;
    __syncthreads();
#pragma unroll
    for (int kk = 0; kk < 16; ++kk) {
      float a[4], b[4];
#pragma unroll
      for (int r = 0; r < 4; ++r) a[r] = As[kk][ty * 4 + r];
#pragma unroll
      for (int c = 0; c < 4; ++c) b[c] = Bs[kk][tx * 4 + c];
#pragma unroll
      for (int r = 0; r < 4; ++r)
#pragma unroll
        for (int c = 0; c < 4; ++c)
          acc[r][c] += a[r] * b[c];
    }
    __syncthreads();
  }
  float bv[4] = {0.f, 0.f, 0.f, 0.f};
  if (bias) {
#pragma unroll
    for (int c = 0; c < 4; ++c) bv[c] = bias[boff + n0 + tx * 4 + c];
  }
#pragma unroll
  for (int r = 0; r < 4; ++r) {
    int m = m0 + ty * 4 + r;
#pragma unroll
    for (int c = 0; c < 4; ++c) {
      int n = n0 + tx * 4 + c;
      float v = acc[r][c] + bv[c];
      if (do_relu) v = fmaxf(v, 0.f);
      if (!kvmode) {
        C[(size_t)m * N + n] = v;
      } else {
        int b = m >> 10, i = m & 1023, h = n >> 5, d = n & 31;
        C[(size_t)((((b << 3) + h) << 5) + d) * 1024 + i] = v;
      }
    }
  }
}

// ---------- fused QKV projection: nt<4 -> q, 4..7 -> kT, 8..11 -> vT ----------
__global__ __launch_bounds__(256) void gemm_qkv_k(
    const float* __restrict__ A, const float* __restrict__ Wq,
    const float* __restrict__ Wk, const float* __restrict__ Wv, size_t beoff,
    float* __restrict__ q, float* __restrict__ kT, float* __restrict__ vT)
{
  __shared__ float As[16][68];
  __shared__ float Bs[16][68];
  int tid = threadIdx.x;
  int nt = blockIdx.x;
  int sel = nt >> 2;
  const float* Bw = (sel == 0) ? Wq : (sel == 1) ? Wk : Wv;
  float* C = (sel == 0) ? q : (sel == 1) ? kT : vT;
  int kvmode = (sel > 0);
  int m0 = blockIdx.y * 64, n0 = (nt & 3) * 64;
  const int N = 256, K = 256;
  int tx = tid & 15, ty = tid >> 4;
  int arow = tid >> 2, acol = (tid & 3) << 2;
  int brow = tid >> 4, bcol = (tid & 15) << 2;
  float acc[4][4] = {{0.f}};
  for (int k0 = 0; k0 < K; k0 += 16) {
    float4 a4 = *(const float4*)(A + (size_t)(m0 + arow) * K + k0 + acol);
    As[acol + 0][arow] = a4.x;
    As[acol + 1][arow] = a4.y;
    As[acol + 2][arow] = a4.z;
    As[acol + 3][arow] = a4.w;
    float4 b4 = *(const float4*)(Bw + beoff + (size_t)(k0 + brow) * N + n0 + bcol);
    Bs[brow][bcol + 0] = b4.x;
    Bs[brow][bcol + 1] = b4.y;
    Bs[brow][bcol + 2] = b4.z;
    Bs[brow][bcol + 3] = b4.w;
    __syncthreads();
#pragma unroll
    for (int kk = 0; kk < 16; ++kk) {
      float a[4], b[4];
#pragma unroll
      for (int r = 0; r < 4; ++r) a[r] = As[kk][ty * 4 + r];
#pragma unroll
      for (int c = 0; c < 4; ++c) b[c] = Bs[kk][tx * 4 + c];
#pragma unroll
      for (int r = 0; r < 4; ++r)
#pragma unroll
        for (int c = 0; c < 4; ++c)
          acc[r][c] += a[r] * b[c];
    }
    __syncthreads();
  }
#pragma unroll
  for (int r = 0; r < 4; ++r) {
    int m = m0 + ty * 4 + r;
#pragma unroll
    for (int c = 0; c < 4; ++c) {
      int n = n0 + tx * 4 + c;
      float v = acc[r][c];
      if (!kvmode) {
        C[(size_t)m * N + n] = v;
      } else {
        int b = m >> 10, i = m & 1023, h = n >> 5, d = n & 31;
        C[(size_t)((((b << 3) + h) << 5) + d) * 1024 + i] = v;
      }
    }
  }
}

// ---------- relation-aware attention v3: block = (b,h,4 i), PV d-sliced ----------
__global__ __launch_bounds__(256) void attn3_k(
    const float* __restrict__ q, const float* __restrict__ kT,
    const float* __restrict__ vT, const float* __restrict__ Ek,
    const float* __restrict__ Ev, const int* __restrict__ rel,
    const int* __restrict__ msk, float* __restrict__ out)
{
  __shared__ float uni[4096];      // phase A: Ek staged (r*33+d); phase B: ps[4][1024]
  __shared__ float qs[128];        // [i][d], pre-scaled
  __shared__ float qek[4 * 101];
  __shared__ float wbin[4 * 101];
  __shared__ float red4[1024];
  __shared__ float ovec[128];

  int tid = threadIdx.x;
  int tile = blockIdx.x & 255;
  int h = (blockIdx.x >> 8) & 7;
  int b = blockIdx.x >> 11;
  int i0 = tile << 2;

  for (int idx = tid; idx < 3200; idx += 256) {
    int r = idx >> 5, d = idx & 31;
    uni[r * 33 + d] = Ek[idx];
  }
  if (tid < 128) {
    int i = tid >> 5, d = tid & 31;
    qs[tid] = q[(((size_t)(b * 1024 + i0 + i) * 8 + h) << 5) + d] * 0.17677669529663687f;
  }
  __syncthreads();

  for (int p = tid; p < 400; p += 256) {
    int i = p / 100, r = p - i * 100;
    float s = 0.f;
#pragma unroll
    for (int d = 0; d < 32; ++d) s += qs[i * 32 + d] * uni[r * 33 + d];
    qek[i * 101 + r] = s;
    wbin[i * 101 + r] = 0.f;
  }
  __syncthreads();  // uni free for ps after this

  const float* kTb = kT + ((size_t)(b * 8 + h) << 15);  // [d][j]
  const float* vTb = vT + ((size_t)(b * 8 + h) << 15);

  // ---- scores ----
  float sc[4][4];
  int rl[4][4];
  float mx[4] = {-3.0e38f, -3.0e38f, -3.0e38f, -3.0e38f};
#pragma unroll
  for (int s = 0; s < 4; ++s) {
    int j = tid + (s << 8);
    float acc[4] = {0.f, 0.f, 0.f, 0.f};
#pragma unroll
    for (int d = 0; d < 32; ++d) {
      float kv = kTb[(d << 10) + j];
#pragma unroll
      for (int i = 0; i < 4; ++i) acc[i] += qs[i * 32 + d] * kv;
    }
#pragma unroll
    for (int i = 0; i < 4; ++i) {
      size_t ro = ((size_t)(b * 1024 + i0 + i) << 10) + j;
      int rv = rel[ro];
      rl[s][i] = rv;
      float a = acc[i] + qek[i * 101 + rv];
      if (msk[ro]) a = -1e20f;
      sc[s][i] = a;
      mx[i] = fmaxf(mx[i], a);
    }
  }

  // ---- 4-way max reduction ----
#pragma unroll
  for (int i = 0; i < 4; ++i) red4[i * 256 + tid] = mx[i];
  __syncthreads();
  for (int off = 128; off > 0; off >>= 1) {
    if (tid < off) {
#pragma unroll
      for (int i = 0; i < 4; ++i)
        red4[i * 256 + tid] = fmaxf(red4[i * 256 + tid], red4[i * 256 + tid + off]);
    }
    __syncthreads();
  }
  float gm[4];
#pragma unroll
  for (int i = 0; i < 4; ++i) gm[i] = red4[i * 256];
  __syncthreads();

  // ---- p = exp(sc-gm), ps store, histogram, denominators ----
  float ts[4] = {0.f, 0.f, 0.f, 0.f};
#pragma unroll
  for (int s = 0; s < 4; ++s) {
    int j = tid + (s << 8);
#pragma unroll
    for (int i = 0; i < 4; ++i) {
      float p = __expf(sc[s][i] - gm[i]);
      uni[i * 1024 + j] = p;
      ts[i] += p;
      atomicAdd(&wbin[i * 101 + rl[s][i]], p);
    }
  }
#pragma unroll
  for (int i = 0; i < 4; ++i) red4[i * 256 + tid] = ts[i];
  __syncthreads();
  for (int off = 128; off > 0; off >>= 1) {
    if (tid < off) {
#pragma unroll
      for (int i = 0; i < 4; ++i)
        red4[i * 256 + tid] += red4[i * 256 + tid + off];
    }
    __syncthreads();
  }
  // red4[i*256] = denominator for row i

  // ---- PV, d-sliced: wave wv covers d in [8wv, 8wv+8), lanes carry 4 i's ----
  int wv = tid >> 6, lane = tid & 63;
  int d0 = wv << 3;
  float acc[4][8];
#pragma unroll
  for (int i = 0; i < 4; ++i)
#pragma unroll
    for (int dl = 0; dl < 8; ++dl) acc[i][dl] = 0.f;
  for (int s = 0; s < 16; ++s) {
    int j = lane + (s << 6);
    float p0 = uni[j], p1 = uni[1024 + j], p2 = uni[2048 + j], p3 = uni[3072 + j];
#pragma unroll
    for (int dl = 0; dl < 8; ++dl) {
      float vv = vTb[((d0 + dl) << 10) + j];
      acc[0][dl] += p0 * vv;
      acc[1][dl] += p1 * vv;
      acc[2][dl] += p2 * vv;
      acc[3][dl] += p3 * vv;
    }
  }
#pragma unroll
  for (int i = 0; i < 4; ++i)
#pragma unroll
    for (int dl = 0; dl < 8; ++dl) {
      float v = acc[i][dl];
#pragma unroll
      for (int off = 32; off > 0; off >>= 1) v += __shfl_xor(v, off, 64);
      if (lane == ((i << 3) | dl)) ovec[i * 32 + d0 + dl] = v;
    }
  __syncthreads();

  // ---- Ev term + normalize + write (128 threads: i = tid>>5, d = tid&31) ----
  if (tid < 128) {
    int i = tid >> 5, d = tid & 31;
    float ev = 0.f;
    for (int r = 0; r < 100; ++r)
      ev += wbin[i * 101 + r] * Ev[(r << 5) + d];
    float ginv = 1.f / red4[i * 256];
    out[(((size_t)(b * 1024 + i0 + i) * 8 + h) << 5) + d] =
        (ovec[i * 32 + d] + ev) * ginv;
  }
}

// ---------- residual + LayerNorm ----------
__global__ __launch_bounds__(256) void ln_k(
    const float* __restrict__ x, const float* __restrict__ o,
    const float* __restrict__ g, const float* __restrict__ bta, size_t eoff,
    float* __restrict__ xo, float* __restrict__ fout)
{
  __shared__ float red[256];
  int row = blockIdx.x, t = threadIdx.x;
  size_t idx = (size_t)row * 256 + t;
  float r = x[idx] + o[idx];
  red[t] = r;
  __syncthreads();
  for (int off = 128; off > 0; off >>= 1) {
    if (t < off) red[t] += red[t + off];
    __syncthreads();
  }
  float mean = red[0] * (1.f / 256.f);
  __syncthreads();
  float dv = r - mean;
  red[t] = dv * dv;
  __syncthreads();
  for (int off = 128; off > 0; off >>= 1) {
    if (t < off) red[t] += red[t + off];
    __syncthreads();
  }
  float var = red[0] * (1.f / 256.f);
  float val = dv * rsqrtf(var + 1e-5f) * g[eoff + t] + bta[eoff + t];
  xo[idx] = val;
  if (fout) fout[idx] = val;
}

extern "C" void kernel_launch(void* const* d_in, const int* in_sizes, int n_in,
                              void* d_out, int out_size, void* d_ws, size_t ws_size,
                              hipStream_t stream) {
  const float* inp  = (const float*)d_in[0];
  const float* Wq   = (const float*)d_in[1];
  const float* Wk   = (const float*)d_in[2];
  const float* Wv   = (const float*)d_in[3];
  const float* Wo   = (const float*)d_in[4];
  const float* bo   = (const float*)d_in[5];
  const float* W1   = (const float*)d_in[6];
  const float* b1   = (const float*)d_in[7];
  const float* W2   = (const float*)d_in[8];
  const float* b2   = (const float*)d_in[9];
  const float* ln1g = (const float*)d_in[10];
  const float* ln1b = (const float*)d_in[11];
  const float* ln2g = (const float*)d_in[12];
  const float* ln2b = (const float*)d_in[13];
  const float* Ek   = (const float*)d_in[14];
  const float* Ev   = (const float*)d_in[15];
  const int*   rel  = (const int*)d_in[16];
  const int*   msk  = (const int*)d_in[17];

  const size_t SZ = 524288;  // 2048*256
  float* x    = (float*)d_ws;
  float* q    = x + SZ;                 // region R: q,kT,vT,attn = 8 MB
  float* kT   = q + SZ;
  float* vT   = kT + SZ;
  float* attn = vT + SZ;
  float* tmp  = attn + SZ;              // 2 MB
  float* ffh  = q;                      // 8 MB alias over R (dead during FF)

  cp_k<<<512, 256, 0, stream>>>(inp, x, (int)SZ);

  dim3 blk(256);
  for (int l = 0; l < 2; ++l) {
    size_t o_w  = (size_t)l * 65536;
    size_t o_b  = (size_t)l * 256;
    size_t o_w1 = (size_t)l * 262144;
    size_t o_b1 = (size_t)l * 1024;

    gemm_qkv_k<<<dim3(12, 32), blk, 0, stream>>>(x, Wq, Wk, Wv, o_w, q, kT, vT);

    attn3_k<<<4096, blk, 0, stream>>>(q, kT, vT, Ek, Ev, rel, msk, attn);

    gemm_k<<<dim3(4, 32), blk, 0, stream>>>(attn, Wo, o_w, bo, o_b, tmp,
                                            2048, 256, 256, 0, 0);
    ln_k<<<2048, blk, 0, stream>>>(x, tmp, ln1g, ln1b, o_b, x, nullptr);

    gemm_k<<<dim3(16, 32), blk, 0, stream>>>(x, W1, o_w1, b1, o_b1, ffh,
                                             2048, 1024, 256, 0, 1);
    gemm_k<<<dim3(4, 32), blk, 0, stream>>>(ffh, W2, o_w1, b2, o_b, tmp,
                                            2048, 256, 1024, 0, 0);
    ln_k<<<2048, blk, 0, stream>>>(x, tmp, ln2g, ln2b, o_b, x,
                                   (l == 1) ? (float*)d_out : nullptr);
  }
}

// Round 14
// 790.639 us; speedup vs baseline: 1.3900x; 1.3900x over previous
//
#include <hip/hip_runtime.h>

// RATSQL relation-aware transformer layer, MI355X.
// Round 14: R13 regressed (VGPR 56->136, occ 43->11.6%, 1 block/CU). Revert to
// R12 register profile (i=wave, oacc[32]); fix L2 traffic via LDS v-chunk
// staging (vT 512->128 KB/block, shared by all 4 waves) and float4/int4
// vectorized score loads (4x fewer vmem instructions). LDS ~29KB -> 5 blk/CU.

typedef unsigned short bf16;

__global__ void cp_k(const float* __restrict__ in, float* __restrict__ out, int n) {
  int i = blockIdx.x * blockDim.x + threadIdx.x;
  int st = gridDim.x * blockDim.x;
  for (; i < n; i += st) out[i] = in[i];
}

// ---------- tiled GEMM: C = act(A(MxK) @ B(KxN) + bias), all fp32 ----------
__global__ __launch_bounds__(256) void gemm_k(
    const float* __restrict__ A, const float* __restrict__ Bw, size_t beoff,
    const float* __restrict__ bias, size_t boff, float* __restrict__ C,
    int M, int N, int K, int kvmode, int do_relu)
{
  __shared__ float As[16][68];
  __shared__ float Bs[16][68];
  int tid = threadIdx.x;
  int m0 = blockIdx.y * 64, n0 = blockIdx.x * 64;
  int tx = tid & 15, ty = tid >> 4;
  int arow = tid >> 2, acol = (tid & 3) << 2;
  int brow = tid >> 4, bcol = (tid & 15) << 2;
  float acc[4][4] = {{0.f}};
  for (int k0 = 0; k0 < K; k0 += 16) {
    float4 a4 = *(const float4*)(A + (size_t)(m0 + arow) * K + k0 + acol);
    As[acol + 0][arow] = a4.x;
    As[acol + 1][arow] = a4.y;
    As[acol + 2][arow] = a4.z;
    As[acol + 3][arow] = a4.w;
    float4 b4 = *(const float4*)(Bw + beoff + (size_t)(k0 + brow) * N + n0 + bcol);
    Bs[brow][bcol + 0] = b4.x;
    Bs[brow][bcol + 1] = b4.y;
    Bs[brow][bcol + 2] = b4.z;
    Bs[brow][bcol + 3] = b4.w;
    __syncthreads();
#pragma unroll
    for (int kk = 0; kk < 16; ++kk) {
      float a[4], b[4];
#pragma unroll
      for (int r = 0; r < 4; ++r) a[r] = As[kk][ty * 4 + r];
#pragma unroll
      for (int c = 0; c < 4; ++c) b[c] = Bs[kk][tx * 4 + c];
#pragma unroll
      for (int r = 0; r < 4; ++r)
#pragma unroll
        for (int c = 0; c < 4; ++c)
          acc[r][c] += a[r] * b[c];
    }
    __syncthreads();
  }
  float bv[4] = {0.f, 0.f, 0.f, 0.f};
  if (bias) {
#pragma unroll
    for (int c = 0; c < 4; ++c) bv[c] = bias[boff + n0 + tx * 4 + c];
  }
#pragma unroll
  for (int r = 0; r < 4; ++r) {
    int m = m0 + ty * 4 + r;
#pragma unroll
    for (int c = 0; c < 4; ++c) {
      int n = n0 + tx * 4 + c;
      float v = acc[r][c] + bv[c];
      if (do_relu) v = fmaxf(v, 0.f);
      if (!kvmode) {
        C[(size_t)m * N + n] = v;
      } else {
        int b = m >> 10, i = m & 1023, h = n >> 5, d = n & 31;
        C[(size_t)((((b << 3) + h) << 5) + d) * 1024 + i] = v;
      }
    }
  }
}

// ---------- fused QKV projection ----------
__global__ __launch_bounds__(256) void gemm_qkv_k(
    const float* __restrict__ A, const float* __restrict__ Wq,
    const float* __restrict__ Wk, const float* __restrict__ Wv, size_t beoff,
    float* __restrict__ q, float* __restrict__ kT, float* __restrict__ vT)
{
  __shared__ float As[16][68];
  __shared__ float Bs[16][68];
  int tid = threadIdx.x;
  int nt = blockIdx.x;
  int sel = nt >> 2;
  const float* Bw = (sel == 0) ? Wq : (sel == 1) ? Wk : Wv;
  float* C = (sel == 0) ? q : (sel == 1) ? kT : vT;
  int kvmode = (sel > 0);
  int m0 = blockIdx.y * 64, n0 = (nt & 3) * 64;
  const int N = 256, K = 256;
  int tx = tid & 15, ty = tid >> 4;
  int arow = tid >> 2, acol = (tid & 3) << 2;
  int brow = tid >> 4, bcol = (tid & 15) << 2;
  float acc[4][4] = {{0.f}};
  for (int k0 = 0; k0 < K; k0 += 16) {
    float4 a4 = *(const float4*)(A + (size_t)(m0 + arow) * K + k0 + acol);
    As[acol + 0][arow] = a4.x;
    As[acol + 1][arow] = a4.y;
    As[acol + 2][arow] = a4.z;
    As[acol + 3][arow] = a4.w;
    float4 b4 = *(const float4*)(Bw + beoff + (size_t)(k0 + brow) * N + n0 + bcol);
    Bs[brow][bcol + 0] = b4.x;
    Bs[brow][bcol + 1] = b4.y;
    Bs[brow][bcol + 2] = b4.z;
    Bs[brow][bcol + 3] = b4.w;
    __syncthreads();
#pragma unroll
    for (int kk = 0; kk < 16; ++kk) {
      float a[4], b[4];
#pragma unroll
      for (int r = 0; r < 4; ++r) a[r] = As[kk][ty * 4 + r];
#pragma unroll
      for (int c = 0; c < 4; ++c) b[c] = Bs[kk][tx * 4 + c];
#pragma unroll
      for (int r = 0; r < 4; ++r)
#pragma unroll
        for (int c = 0; c < 4; ++c)
          acc[r][c] += a[r] * b[c];
    }
    __syncthreads();
  }
#pragma unroll
  for (int r = 0; r < 4; ++r) {
    int m = m0 + ty * 4 + r;
#pragma unroll
    for (int c = 0; c < 4; ++c) {
      int n = n0 + tx * 4 + c;
      float v = acc[r][c];
      if (!kvmode) {
        C[(size_t)m * N + n] = v;
      } else {
        int b = m >> 10, i = m & 1023, h = n >> 5, d = n & 31;
        C[(size_t)((((b << 3) + h) << 5) + d) * 1024 + i] = v;
      }
    }
  }
}

// ---------- attention v4: R12 structure + v-chunk LDS staging + float4 scores ----------
__global__ __launch_bounds__(256) void attn4_k(
    const float* __restrict__ q, const float* __restrict__ kT,
    const float* __restrict__ vT, const float* __restrict__ Ek,
    const float* __restrict__ Ev, const int* __restrict__ rel,
    const int* __restrict__ msk, float* __restrict__ out)
{
  __shared__ float uni[4096];      // phase A: Ek (r*33+d); phase B: ps[4][1024]
  __shared__ float qs[128];        // [i][d], pre-scaled
  __shared__ float qek[4 * 101];   // [..][100] later holds denominator
  __shared__ float wbin[4 * 101];
  __shared__ float scr[2176];      // union: reductions (1024) / v-chunk 32x68
  __shared__ float ovec[128];

  int tid = threadIdx.x;
  int tile = blockIdx.x & 255;
  int h = (blockIdx.x >> 8) & 7;
  int b = blockIdx.x >> 11;
  int i0 = tile << 2;

  for (int idx = tid; idx < 3200; idx += 256) {
    int r = idx >> 5, d = idx & 31;
    uni[r * 33 + d] = Ek[idx];
  }
  if (tid < 128) {
    int i = tid >> 5, d = tid & 31;
    qs[tid] = q[(((size_t)(b * 1024 + i0 + i) * 8 + h) << 5) + d] * 0.17677669529663687f;
  }
  __syncthreads();

  for (int p = tid; p < 400; p += 256) {
    int i = p / 100, r = p - i * 100;
    float s = 0.f;
#pragma unroll
    for (int d = 0; d < 32; ++d) s += qs[i * 32 + d] * uni[r * 33 + d];
    qek[i * 101 + r] = s;
    wbin[i * 101 + r] = 0.f;
  }
  __syncthreads();  // uni free for ps after this

  const float* kTb = kT + ((size_t)(b * 8 + h) << 15);  // [d][j]
  const float* vTb = vT + ((size_t)(b * 8 + h) << 15);

  // ---- scores: thread covers contiguous j = 4*tid..4*tid+3, all 4 i ----
  int j0 = tid << 2;
  float sc4[4][4];  // [jj][i]
#pragma unroll
  for (int jj = 0; jj < 4; ++jj)
#pragma unroll
    for (int i = 0; i < 4; ++i) sc4[jj][i] = 0.f;
#pragma unroll
  for (int d = 0; d < 32; ++d) {
    float4 kv = *(const float4*)(kTb + (d << 10) + j0);
#pragma unroll
    for (int i = 0; i < 4; ++i) {
      float qv = qs[i * 32 + d];
      sc4[0][i] += qv * kv.x;
      sc4[1][i] += qv * kv.y;
      sc4[2][i] += qv * kv.z;
      sc4[3][i] += qv * kv.w;
    }
  }
  int rl[4][4];  // [jj][i]
  float mx[4] = {-3.0e38f, -3.0e38f, -3.0e38f, -3.0e38f};
#pragma unroll
  for (int i = 0; i < 4; ++i) {
    size_t ro = ((size_t)(b * 1024 + i0 + i) << 10) + j0;
    int4 rv = *(const int4*)(rel + ro);
    int4 mv = *(const int4*)(msk + ro);
    rl[0][i] = rv.x; rl[1][i] = rv.y; rl[2][i] = rv.z; rl[3][i] = rv.w;
    float a0 = sc4[0][i] + qek[i * 101 + rv.x];
    float a1 = sc4[1][i] + qek[i * 101 + rv.y];
    float a2 = sc4[2][i] + qek[i * 101 + rv.z];
    float a3 = sc4[3][i] + qek[i * 101 + rv.w];
    if (mv.x) a0 = -1e20f;
    if (mv.y) a1 = -1e20f;
    if (mv.z) a2 = -1e20f;
    if (mv.w) a3 = -1e20f;
    sc4[0][i] = a0; sc4[1][i] = a1; sc4[2][i] = a2; sc4[3][i] = a3;
    mx[i] = fmaxf(mx[i], fmaxf(fmaxf(a0, a1), fmaxf(a2, a3)));
  }

  // ---- 4-way max reduction (scr) ----
#pragma unroll
  for (int i = 0; i < 4; ++i) scr[i * 256 + tid] = mx[i];
  __syncthreads();
  for (int off = 128; off > 0; off >>= 1) {
    if (tid < off) {
#pragma unroll
      for (int i = 0; i < 4; ++i)
        scr[i * 256 + tid] = fmaxf(scr[i * 256 + tid], scr[i * 256 + tid + off]);
    }
    __syncthreads();
  }
  float gm[4];
#pragma unroll
  for (int i = 0; i < 4; ++i) gm[i] = scr[i * 256];
  __syncthreads();

  // ---- p = exp(sc-gm), ps store, histogram, denominators ----
  float ts[4] = {0.f, 0.f, 0.f, 0.f};
#pragma unroll
  for (int i = 0; i < 4; ++i) {
#pragma unroll
    for (int jj = 0; jj < 4; ++jj) {
      float p = __expf(sc4[jj][i] - gm[i]);
      uni[(i << 10) + j0 + jj] = p;
      ts[i] += p;
      atomicAdd(&wbin[i * 101 + rl[jj][i]], p);
    }
  }
#pragma unroll
  for (int i = 0; i < 4; ++i) scr[i * 256 + tid] = ts[i];
  __syncthreads();
  for (int off = 128; off > 0; off >>= 1) {
    if (tid < off) {
#pragma unroll
      for (int i = 0; i < 4; ++i)
        scr[i * 256 + tid] += scr[i * 256 + tid + off];
    }
    __syncthreads();
  }
  if (tid < 4) qek[tid * 101 + 100] = scr[tid * 256];  // park denominators

  // ---- PV: wave wv = i; v staged per 64-j chunk in scr (pad 68) ----
  int wv = tid >> 6, lane = tid & 63;
  float oacc[32];
#pragma unroll
  for (int d = 0; d < 32; ++d) oacc[d] = 0.f;
  for (int c = 0; c < 16; ++c) {
    __syncthreads();  // previous chunk consumed / scr free
    for (int e4 = tid; e4 < 512; e4 += 256) {
      int d = e4 >> 4, jl4 = (e4 & 15) << 2;
      *(float4*)(scr + d * 68 + jl4) = *(const float4*)(vTb + (d << 10) + (c << 6) + jl4);
    }
    __syncthreads();
    float p = uni[(wv << 10) + (c << 6) + lane];
#pragma unroll
    for (int d = 0; d < 32; ++d)
      oacc[d] += p * scr[d * 68 + lane];
  }
#pragma unroll
  for (int d = 0; d < 32; ++d) {
    float v = oacc[d];
#pragma unroll
    for (int off = 32; off > 0; off >>= 1) v += __shfl_xor(v, off, 64);
    if (lane == d) ovec[wv * 32 + d] = v;
  }
  __syncthreads();

  // ---- Ev term + normalize + write ----
  if (tid < 128) {
    int i = tid >> 5, d = tid & 31;
    float ev = 0.f;
    for (int r = 0; r < 100; ++r)
      ev += wbin[i * 101 + r] * Ev[(r << 5) + d];
    float ginv = 1.f / qek[i * 101 + 100];
    out[(((size_t)(b * 1024 + i0 + i) * 8 + h) << 5) + d] =
        (ovec[i * 32 + d] + ev) * ginv;
  }
}

// ---------- residual + LayerNorm ----------
__global__ __launch_bounds__(256) void ln_k(
    const float* __restrict__ x, const float* __restrict__ o,
    const float* __restrict__ g, const float* __restrict__ bta, size_t eoff,
    float* __restrict__ xo, float* __restrict__ fout)
{
  __shared__ float red[256];
  int row = blockIdx.x, t = threadIdx.x;
  size_t idx = (size_t)row * 256 + t;
  float r = x[idx] + o[idx];
  red[t] = r;
  __syncthreads();
  for (int off = 128; off > 0; off >>= 1) {
    if (t < off) red[t] += red[t + off];
    __syncthreads();
  }
  float mean = red[0] * (1.f / 256.f);
  __syncthreads();
  float dv = r - mean;
  red[t] = dv * dv;
  __syncthreads();
  for (int off = 128; off > 0; off >>= 1) {
    if (t < off) red[t] += red[t + off];
    __syncthreads();
  }
  float var = red[0] * (1.f / 256.f);
  float val = dv * rsqrtf(var + 1e-5f) * g[eoff + t] + bta[eoff + t];
  xo[idx] = val;
  if (fout) fout[idx] = val;
}

extern "C" void kernel_launch(void* const* d_in, const int* in_sizes, int n_in,
                              void* d_out, int out_size, void* d_ws, size_t ws_size,
                              hipStream_t stream) {
  const float* inp  = (const float*)d_in[0];
  const float* Wq   = (const float*)d_in[1];
  const float* Wk   = (const float*)d_in[2];
  const float* Wv   = (const float*)d_in[3];
  const float* Wo   = (const float*)d_in[4];
  const float* bo   = (const float*)d_in[5];
  const float* W1   = (const float*)d_in[6];
  const float* b1   = (const float*)d_in[7];
  const float* W2   = (const float*)d_in[8];
  const float* b2   = (const float*)d_in[9];
  const float* ln1g = (const float*)d_in[10];
  const float* ln1b = (const float*)d_in[11];
  const float* ln2g = (const float*)d_in[12];
  const float* ln2b = (const float*)d_in[13];
  const float* Ek   = (const float*)d_in[14];
  const float* Ev   = (const float*)d_in[15];
  const int*   rel  = (const int*)d_in[16];
  const int*   msk  = (const int*)d_in[17];

  const size_t SZ = 524288;  // 2048*256
  float* x    = (float*)d_ws;
  float* q    = x + SZ;                 // region R: q,kT,vT,attn = 8 MB
  float* kT   = q + SZ;
  float* vT   = kT + SZ;
  float* attn = vT + SZ;
  float* tmp  = attn + SZ;              // 2 MB
  float* ffh  = q;                      // 8 MB alias over R (dead during FF)

  cp_k<<<512, 256, 0, stream>>>(inp, x, (int)SZ);

  dim3 blk(256);
  for (int l = 0; l < 2; ++l) {
    size_t o_w  = (size_t)l * 65536;
    size_t o_b  = (size_t)l * 256;
    size_t o_w1 = (size_t)l * 262144;
    size_t o_b1 = (size_t)l * 1024;

    gemm_qkv_k<<<dim3(12, 32), blk, 0, stream>>>(x, Wq, Wk, Wv, o_w, q, kT, vT);

    attn4_k<<<4096, blk, 0, stream>>>(q, kT, vT, Ek, Ev, rel, msk, attn);

    gemm_k<<<dim3(4, 32), blk, 0, stream>>>(attn, Wo, o_w, bo, o_b, tmp,
                                            2048, 256, 256, 0, 0);
    ln_k<<<2048, blk, 0, stream>>>(x, tmp, ln1g, ln1b, o_b, x, nullptr);

    gemm_k<<<dim3(16, 32), blk, 0, stream>>>(x, W1, o_w1, b1, o_b1, ffh,
                                             2048, 1024, 256, 0, 1);
    gemm_k<<<dim3(4, 32), blk, 0, stream>>>(ffh, W2, o_w1, b2, o_b, tmp,
                                            2048, 256, 1024, 0, 0);
    ln_k<<<2048, blk, 0, stream>>>(x, tmp, ln2g, ln2b, o_b, x,
                                   (l == 1) ? (float*)d_out : nullptr);
  }
}